// Round 2
// baseline (1188.579 us; speedup 1.0000x reference)
//
#include <hip/hip_runtime.h>
#include <hip/hip_bf16.h>

typedef unsigned short u16;
typedef unsigned int   u32;

#define N_   32
#define T_   32
#define V_   128
#define CIN_ 264
#define CO_  64
#define KT_  9
#define EPS_ 1e-3f

// ---- param table (float offsets inside ws) ----
#define OFF_DBN_S 0          // 33792
#define OFF_DBN_O 33792      // 33792
#define OFF_W0    67584      // 264*64
#define OFF_BW0   84480      // 64
#define OFF_A0S   84544
#define OFF_A0O   84608
#define OFF_B0S   84672      // includes bt0 fold
#define OFF_B0O   84736
#define OFF_W1    84800      // 64*64
#define OFF_BW1   88896
#define OFF_A1S   88960
#define OFF_A1O   89024
#define OFF_B1S   89088      // includes bt1 fold
#define OFF_B1O   89152
#define PREP_TOTAL 55168

// ---- ws byte layout ----
#define B_FLAG 360448                    // int, after P's 356864 used bytes
#define B_P    0
#define B_H0   524288                    // bf16 N*64*T*V
#define B_G0   (B_H0 + 16777216)         // bf16 N*64*T*V
#define B_L0   (B_G0 + 16777216)         // f32  N*64*T*V
#define B_G1P  (B_L0 + 33554432)         // f32  N*64*T
#define B_END  (B_G1P + 262144)

__device__ __forceinline__ float bf2f(u16 u) { return __uint_as_float(((u32)u) << 16); }
__device__ __forceinline__ u16 f2bf(float f) {
    u32 x = __float_as_uint(f);
    return (u16)((x + 0x7fffu + ((x >> 16) & 1u)) >> 16);
}
// dtype-adaptive global load: flag==1 -> buffer is float32, else bf16
__device__ __forceinline__ float ldin(const void* p, u32 i, int f32) {
    return f32 ? ((const float*)p)[i] : bf2f(((const u16*)p)[i]);
}

// ---------------- dtype detect: sample even u16 indices of 'a' (uniform [0,1]) ----------------
// bf16 buffer: even u16s are real elements, all in [0,1]. fp32 buffer: even u16s are
// low mantissa halves -> random bits -> ~25% land in [0,1]. Clean separation at 56/64.
__global__ void k_detect(const void* a, int* flag) {
    if (threadIdx.x == 0 && blockIdx.x == 0) {
        const u16* p = (const u16*)a;
        int cnt = 0;
        for (int i = 0; i < 64; ++i) {
            float v = bf2f(p[2 * i]);
            if (v >= 0.f && v <= 1.0f) ++cnt;
        }
        *flag = (cnt >= 56) ? 0 : 1;
    }
}

// ---------------- param prep: fold all BN affines into scale/offset, store fp32 ----------------
__global__ void k_prep(const void* dbn_g, const void* dbn_b, const void* dbn_m, const void* dbn_v,
                       const void* w0, const void* bw0,
                       const void* g0a, const void* b0a, const void* m0a, const void* v0a,
                       const void* bt0, const void* g0b, const void* b0b, const void* m0b, const void* v0b,
                       const void* w1, const void* bw1,
                       const void* g1a, const void* b1a, const void* m1a, const void* v1a,
                       const void* bt1, const void* g1b, const void* b1b, const void* m1b, const void* v1b,
                       float* P, const int* flagp)
{
    const int f32 = *flagp;
    int i = blockIdx.x * 256 + threadIdx.x;
    if (i < 33792) {
        float s = ldin(dbn_g, i, f32) * rsqrtf(ldin(dbn_v, i, f32) + EPS_);
        P[OFF_DBN_S + i] = s;
        P[OFF_DBN_O + i] = ldin(dbn_b, i, f32) - ldin(dbn_m, i, f32) * s;
    } else if (i < 50688) { int j = i - 33792; P[OFF_W0 + j] = ldin(w0, j, f32); }
    else if (i < 50752) { int j = i - 50688; P[OFF_BW0 + j] = ldin(bw0, j, f32); }
    else if (i < 50816) { int j = i - 50752;
        float s = ldin(g0a, j, f32) * rsqrtf(ldin(v0a, j, f32) + EPS_);
        P[OFF_A0S + j] = s; P[OFF_A0O + j] = ldin(b0a, j, f32) - ldin(m0a, j, f32) * s;
    } else if (i < 50880) { int j = i - 50816;
        float s = ldin(g0b, j, f32) * rsqrtf(ldin(v0b, j, f32) + EPS_);
        P[OFF_B0S + j] = s; P[OFF_B0O + j] = (ldin(bt0, j, f32) - ldin(m0b, j, f32)) * s + ldin(b0b, j, f32);
    } else if (i < 54976) { int j = i - 50880; P[OFF_W1 + j] = ldin(w1, j, f32); }
    else if (i < 55040) { int j = i - 54976; P[OFF_BW1 + j] = ldin(bw1, j, f32); }
    else if (i < 55104) { int j = i - 55040;
        float s = ldin(g1a, j, f32) * rsqrtf(ldin(v1a, j, f32) + EPS_);
        P[OFF_A1S + j] = s; P[OFF_A1O + j] = ldin(b1a, j, f32) - ldin(m1a, j, f32) * s;
    } else if (i < 55168) { int j = i - 55104;
        float s = ldin(g1b, j, f32) * rsqrtf(ldin(v1b, j, f32) + EPS_);
        P[OFF_B1S + j] = s; P[OFF_B1O + j] = (ldin(bt1, j, f32) - ldin(m1b, j, f32)) * s + ldin(b1b, j, f32);
    }
}

// ---------------- fused concat + data-BN + flat-reshape gather + pointwise conv 0 ----------------
// block = (t2, n), 128 threads (v2). xs staged in 2 halves of 132 channels (33.8KB LDS).
__global__ __launch_bounds__(128) void k_pw0(const void* __restrict__ xin, const void* __restrict__ bin,
                                             const void* __restrict__ cin2, const float* __restrict__ P,
                                             u16* __restrict__ h0, const int* __restrict__ flagp)
{
    __shared__ u16 xs[132 * V_];
    const int f32 = *flagp;
    const int t2 = blockIdx.x, n = blockIdx.y;
    const int tid = threadIdx.x;
    float acc[CO_];
#pragma unroll
    for (int o = 0; o < CO_; ++o) acc[o] = P[OFF_BW0 + o];

    const int v2 = tid;
    for (int half = 0; half < 2; ++half) {
        if (half) __syncthreads();
        const int cbase = half * 132;
        for (int e = tid; e < 132 * V_; e += 128) {
            int c2 = cbase + (e >> 7); int vv = e & 127;
            u32 L = (u32)c2 * 4096u + (u32)t2 * 128u + (u32)vv;
            u32 vs = L / 8448u;
            u32 r  = L - vs * 8448u;
            u32 ts = r / 264u;
            u32 cc = r - ts * 264u;
            u32 base = ((u32)n * 32u + ts) * 128u + vs;
            float val;
            if (cc < 256u)      val = ldin(xin, base * 256u + cc, f32);
            else if (cc < 260u) val = ldin(bin, base * 4u + (cc - 256u), f32);
            else                val = ldin(cin2, base * 4u + (cc - 260u), f32);
            u32 ch = vs * 264u + cc;
            xs[e] = f2bf(fmaf(val, P[OFF_DBN_S + ch], P[OFF_DBN_O + ch]));
        }
        __syncthreads();
        const float* W = P + OFF_W0 + cbase * CO_;
        for (int c = 0; c < 132; ++c) {
            float xv = bf2f(xs[c * V_ + v2]);
            const float* wr = W + c * CO_;
#pragma unroll
            for (int o = 0; o < CO_; ++o) acc[o] = fmaf(xv, wr[o], acc[o]);
        }
    }
    const u32 ob = (u32)n * (CO_ * T_ * V_) + (u32)t2 * V_ + (u32)v2;
#pragma unroll
    for (int o = 0; o < CO_; ++o) h0[ob + (u32)o * (T_ * V_)] = f2bf(acc[o]);
}

// ---------------- graph conv 0 + BN0a + PReLU ----------------
// block = (t, n), 256 threads, tile 8c x 4w per thread. LDS: am bf16 32KB + hl f32 32KB.
__global__ __launch_bounds__(256) void k_graph0(const void* __restrict__ a, const void* __restrict__ imp0,
                                                const void* __restrict__ al0, const float* __restrict__ P,
                                                const u16* __restrict__ h0, u16* __restrict__ g0,
                                                const int* __restrict__ flagp)
{
    __shared__ u16 am[V_ * V_];
    __shared__ float hl[CO_ * V_];
    const int f32 = *flagp;
    const int t = blockIdx.x, n = blockIdx.y;
    const int tid = threadIdx.x;
    const u32 abase = (((u32)n * T_ + t) * V_) * V_;
    for (int e = tid; e < V_ * V_; e += 256)
        am[e] = f2bf(ldin(a, abase + (u32)e, f32) * ldin(imp0, (u32)e, f32));
    const u32 hbase = (u32)n * (CO_ * T_ * V_) + (u32)t * V_;
    for (int e = tid; e < CO_ * V_; e += 256) {
        int c = e >> 7, v = e & 127;
        hl[e] = bf2f(h0[hbase + (u32)c * (T_ * V_) + (u32)v]);
    }
    __syncthreads();
    const int w4 = (tid & 31) << 2;
    const int c0 = (tid >> 5) << 3;
    float acc[8][4];
#pragma unroll
    for (int j = 0; j < 8; ++j) { acc[j][0] = acc[j][1] = acc[j][2] = acc[j][3] = 0.f; }

    for (int v0 = 0; v0 < V_; v0 += 4) {
        float amf[4][4];
#pragma unroll
        for (int vv = 0; vv < 4; ++vv) {
            uint2 a4 = *(const uint2*)&am[(v0 + vv) * V_ + w4];
            amf[vv][0] = __uint_as_float(a4.x << 16);
            amf[vv][1] = __uint_as_float(a4.x & 0xffff0000u);
            amf[vv][2] = __uint_as_float(a4.y << 16);
            amf[vv][3] = __uint_as_float(a4.y & 0xffff0000u);
        }
        float hv[8][4];
#pragma unroll
        for (int j = 0; j < 8; ++j) {
            float4 hq = *(const float4*)&hl[(c0 + j) * V_ + v0];
            hv[j][0] = hq.x; hv[j][1] = hq.y; hv[j][2] = hq.z; hv[j][3] = hq.w;
        }
#pragma unroll
        for (int vv = 0; vv < 4; ++vv)
#pragma unroll
            for (int j = 0; j < 8; ++j) {
                acc[j][0] = fmaf(hv[j][vv], amf[vv][0], acc[j][0]);
                acc[j][1] = fmaf(hv[j][vv], amf[vv][1], acc[j][1]);
                acc[j][2] = fmaf(hv[j][vv], amf[vv][2], acc[j][2]);
                acc[j][3] = fmaf(hv[j][vv], amf[vv][3], acc[j][3]);
            }
    }
#pragma unroll
    for (int j = 0; j < 8; ++j) {
        const int c = c0 + j;
        const float s = P[OFF_A0S + c], ofs = P[OFF_A0O + c];
        ushort4 rr; u16* rp = (u16*)&rr;
#pragma unroll
        for (int q = 0; q < 4; ++q) {
            float y = fmaf(acc[j][q], s, ofs);
            float alv = ldin(al0, ((u32)c * T_ + t) * V_ + (w4 + q), f32);
            rp[q] = f2bf((y >= 0.f) ? y : alv * y);
        }
        *(ushort4*)&g0[(u32)n * (CO_ * T_ * V_) + (u32)c * (T_ * V_) + (u32)t * V_ + w4] = rr;
    }
}

// ---------------- temporal conv 0 (K=9) + BN0b(+bt0) -> L0 (f32) ----------------
// block = (t, n), 256 threads, tile 8o x 4v. ps slice (9x128 f32) in LDS per input channel i.
__global__ __launch_bounds__(256) void k_tconv0(const void* __restrict__ wt0, const float* __restrict__ P,
                                                const u16* __restrict__ g0, float* __restrict__ L0,
                                                const int* __restrict__ flagp)
{
    __shared__ float ps[KT_ * V_];
    const int f32 = *flagp;
    const int t = blockIdx.x, n = blockIdx.y;
    const int tid = threadIdx.x;
    const int o0 = (tid >> 5) << 3;
    const int v0 = (tid & 31) << 2;
    float acc[8][4];
#pragma unroll
    for (int j = 0; j < 8; ++j) { acc[j][0] = acc[j][1] = acc[j][2] = acc[j][3] = 0.f; }

    for (int i = 0; i < CO_; ++i) {
        __syncthreads();
        for (int e = tid; e < KT_ * V_; e += 256) {
            int k = e >> 7, v = e & 127;
            int tt = t + k - 4;
            ps[e] = (tt >= 0 && tt < T_)
                  ? bf2f(g0[(u32)n * (CO_ * T_ * V_) + (u32)i * (T_ * V_) + (u32)tt * V_ + v]) : 0.f;
        }
        __syncthreads();
#pragma unroll
        for (int k = 0; k < KT_; ++k) {
            const float4 pv = *(const float4*)&ps[k * V_ + v0];
            float wf[8];
            if (f32) {
                const float4* wp = (const float4*)((const float*)wt0 + ((u32)(k * CO_ + i)) * CO_ + o0);
                float4 wa = wp[0], wb = wp[1];
                wf[0] = wa.x; wf[1] = wa.y; wf[2] = wa.z; wf[3] = wa.w;
                wf[4] = wb.x; wf[5] = wb.y; wf[6] = wb.z; wf[7] = wb.w;
            } else {
                const uint4 wr = *(const uint4*)((const u16*)wt0 + ((u32)(k * CO_ + i)) * CO_ + o0);
                wf[0] = __uint_as_float(wr.x << 16); wf[1] = __uint_as_float(wr.x & 0xffff0000u);
                wf[2] = __uint_as_float(wr.y << 16); wf[3] = __uint_as_float(wr.y & 0xffff0000u);
                wf[4] = __uint_as_float(wr.z << 16); wf[5] = __uint_as_float(wr.z & 0xffff0000u);
                wf[6] = __uint_as_float(wr.w << 16); wf[7] = __uint_as_float(wr.w & 0xffff0000u);
            }
#pragma unroll
            for (int j = 0; j < 8; ++j) {
                acc[j][0] = fmaf(wf[j], pv.x, acc[j][0]);
                acc[j][1] = fmaf(wf[j], pv.y, acc[j][1]);
                acc[j][2] = fmaf(wf[j], pv.z, acc[j][2]);
                acc[j][3] = fmaf(wf[j], pv.w, acc[j][3]);
            }
        }
    }
#pragma unroll
    for (int j = 0; j < 8; ++j) {
        const int o = o0 + j;
        const float s = P[OFF_B0S + o], ofs = P[OFF_B0O + o];
        float4 r;
        r.x = fmaf(acc[j][0], s, ofs); r.y = fmaf(acc[j][1], s, ofs);
        r.z = fmaf(acc[j][2], s, ofs); r.w = fmaf(acc[j][3], s, ofs);
        *(float4*)&L0[(u32)n * (CO_ * T_ * V_) + (u32)o * (T_ * V_) + (u32)t * V_ + v0] = r;
    }
}

// ---------------- pointwise conv 1 + graph conv 1 (w=0 only) + BN1a + PReLU -> g1p ----------------
// block = (t, n), 128 threads (v). h1 never materialized; reduce over v in LDS.
__global__ __launch_bounds__(128) void k_pw1(const void* __restrict__ a, const void* __restrict__ imp1,
                                             const void* __restrict__ al1, const float* __restrict__ P,
                                             const float* __restrict__ L0, float* __restrict__ g1p,
                                             const int* __restrict__ flagp)
{
    __shared__ float part[V_ * 65];
    __shared__ float red2[128];
    const int f32 = *flagp;
    const int t = blockIdx.x, n = blockIdx.y;
    const int tid = threadIdx.x;
    const int v = tid;
    float acc[CO_];
#pragma unroll
    for (int o = 0; o < CO_; ++o) acc[o] = P[OFF_BW1 + o];
    const float* W = P + OFF_W1;
    const u32 base = (u32)n * (CO_ * T_ * V_) + (u32)t * V_ + (u32)v;
    for (int c = 0; c < CO_; ++c) {
        float xv = L0[base + (u32)c * (T_ * V_)];
        const float* wr = W + c * CO_;
#pragma unroll
        for (int o = 0; o < CO_; ++o) acc[o] = fmaf(xv, wr[o], acc[o]);
    }
    float amv = ldin(a, (((u32)n * T_ + t) * V_ + v) * V_ + 0u, f32) * ldin(imp1, (u32)v * V_ + 0u, f32);
#pragma unroll
    for (int o = 0; o < CO_; ++o) part[v * 65 + o] = acc[o] * amv;
    __syncthreads();
    const int o = tid & 63, hh = tid >> 6;
    float s = 0.f;
    for (int vv = hh * 64; vv < hh * 64 + 64; ++vv) s += part[vv * 65 + o];
    red2[tid] = s;
    __syncthreads();
    if (tid < 64) {
        float g = red2[tid] + red2[64 + tid];
        float y = fmaf(g, P[OFF_A1S + o], P[OFF_A1O + o]);
        float alv = ldin(al1, ((u32)o * T_ + t) * V_ + 0u, f32);
        y = (y >= 0.f) ? y : alv * y;
        g1p[((u32)n * CO_ + o) * T_ + t] = y;
    }
}

// ---------------- temporal conv 1 (v=0 only) + BN1b(+bt1) + residual + transpose-out ----------------
// block = (t, n), 64 threads (o). Output store is dtype-adaptive.
__global__ __launch_bounds__(64) void k_tconv1(const void* __restrict__ wt1, const float* __restrict__ P,
                                               const float* __restrict__ g1p, const float* __restrict__ L0,
                                               void* __restrict__ out, const int* __restrict__ flagp)
{
    __shared__ float gl[CO_ * KT_];
    const int f32 = *flagp;
    const int t = blockIdx.x, n = blockIdx.y;
    const int tid = threadIdx.x;
    for (int e = tid; e < CO_ * KT_; e += 64) {
        int i = e / KT_, kk = e - i * KT_;
        int tt = t + kk - 4;
        gl[e] = (tt >= 0 && tt < T_) ? g1p[((u32)n * CO_ + i) * T_ + tt] : 0.f;
    }
    __syncthreads();
    float acc = 0.f;
    for (int i = 0; i < CO_; ++i) {
#pragma unroll
        for (int k = 0; k < KT_; ++k) {
            float wv = ldin(wt1, ((u32)(k * CO_ + i)) * CO_ + tid, f32);
            acc = fmaf(gl[i * KT_ + k], wv, acc);
        }
    }
    float y = fmaf(acc, P[OFF_B1S + tid], P[OFF_B1O + tid]);
    y += L0[(u32)n * (CO_ * T_ * V_) + (u32)tid * (T_ * V_) + (u32)t * V_ + 0];
    const u32 oi = ((u32)n * T_ + t) * CO_ + tid;
    if (f32) ((float*)out)[oi] = y;
    else     ((u16*)out)[oi]   = f2bf(y);
}

// distinctive failure marker if ws too small (absmax -> inf tells me it was ws, not math)
__global__ void k_fail(u16* out, int nel) {
    int i = blockIdx.x * 256 + threadIdx.x;
    if (i < nel) out[i] = 0x7f80; // +inf bf16
}

extern "C" void kernel_launch(void* const* d_in, const int* in_sizes, int n_in,
                              void* d_out, int out_size, void* d_ws, size_t ws_size,
                              hipStream_t stream)
{
    const void* xin  = d_in[0];
    const void* bin  = d_in[1];
    const void* cin2 = d_in[2];
    const void* a    = d_in[3];
    const void* dbn_g = d_in[4];
    const void* dbn_b = d_in[5];
    const void* dbn_m = d_in[6];
    const void* dbn_v = d_in[7];
    const void* w0  = d_in[8];
    const void* bw0 = d_in[9];
    const void* imp0 = d_in[10];
    const void* g0a = d_in[11];
    const void* b0a = d_in[12];
    const void* m0a = d_in[13];
    const void* v0a = d_in[14];
    const void* al0 = d_in[15];
    const void* wt0 = d_in[16];
    const void* bt0 = d_in[17];
    const void* g0b = d_in[18];
    const void* b0b = d_in[19];
    const void* m0b = d_in[20];
    const void* v0b = d_in[21];
    const void* w1  = d_in[22];
    const void* bw1 = d_in[23];
    const void* imp1 = d_in[24];
    const void* g1a = d_in[25];
    const void* b1a = d_in[26];
    const void* m1a = d_in[27];
    const void* v1a = d_in[28];
    const void* al1 = d_in[29];
    const void* wt1 = d_in[30];
    const void* bt1 = d_in[31];
    const void* g1b = d_in[32];
    const void* b1b = d_in[33];
    const void* m1b = d_in[34];
    const void* v1b = d_in[35];

    if (ws_size < (size_t)B_END) {
        k_fail<<<(out_size + 255) / 256, 256, 0, stream>>>((u16*)d_out, out_size);
        return;
    }
    char* w = (char*)d_ws;
    float* P   = (float*)(w + B_P);
    int*   flg = (int*)(w + B_FLAG);
    u16*   h0  = (u16*)(w + B_H0);
    u16*   g0  = (u16*)(w + B_G0);
    float* L0  = (float*)(w + B_L0);
    float* g1p = (float*)(w + B_G1P);

    k_detect<<<1, 64, 0, stream>>>(a, flg);
    k_prep<<<(PREP_TOTAL + 255) / 256, 256, 0, stream>>>(
        dbn_g, dbn_b, dbn_m, dbn_v, w0, bw0, g0a, b0a, m0a, v0a,
        bt0, g0b, b0b, m0b, v0b, w1, bw1, g1a, b1a, m1a, v1a,
        bt1, g1b, b1b, m1b, v1b, P, flg);

    dim3 grid(T_, N_);
    k_pw0   <<<grid, 128, 0, stream>>>(xin, bin, cin2, P, h0, flg);
    k_graph0<<<grid, 256, 0, stream>>>(a, imp0, al0, P, h0, g0, flg);
    k_tconv0<<<grid, 256, 0, stream>>>(wt0, P, g0, L0, flg);
    k_pw1   <<<grid, 128, 0, stream>>>(a, imp1, al1, P, L0, g1p, flg);
    k_tconv1<<<grid,  64, 0, stream>>>(wt1, P, g1p, L0, d_out, flg);
}

// Round 3
// 597.932 us; speedup vs baseline: 1.9878x; 1.9878x over previous
//
#include <hip/hip_runtime.h>
#include <hip/hip_bf16.h>

typedef unsigned short u16;
typedef unsigned int   u32;

#define N_   32
#define T_   32
#define V_   128
#define CIN_ 264
#define CO_  64
#define KT_  9
#define EPS_ 1e-3f

// ---- param table (float offsets inside ws) ----
#define OFF_DBN_S 0          // 33792
#define OFF_DBN_O 33792      // 33792
#define OFF_W0    67584      // 264*64 (f32 copy, unused by mfma path; harmless)
#define OFF_BW0   84480      // 64
#define OFF_A0S   84544
#define OFF_A0O   84608
#define OFF_B0S   84672      // includes bt0 fold
#define OFF_B0O   84736
#define OFF_W1    84800      // 64*64 f32 (pw1)
#define OFF_BW1   88896
#define OFF_A1S   88960
#define OFF_A1O   89024
#define OFF_B1S   89088      // includes bt1 fold
#define OFF_B1O   89152
#define PREP_TOTAL 110464    // + W0A (64*288) + WTA (9*64*64)

// ---- ws byte layout (identical footprint to round-2 proven layout) ----
#define B_P    0
#define B_FLAG 360448
#define B_W0A  360512                    // bf16 64 x 288  (36864 B)
#define B_WTA  397440                    // bf16 9 x 64 x 64 (73728 B)
#define B_H0   524288                    // bf16 [n][c][t][v]  16 MB
#define B_G0   (B_H0 + 16777216)         // bf16 [n][t][v][i]  16 MB
#define B_L0   (B_G0 + 16777216)         // f32  [n][c][t][v]  64 MB
#define B_G1P  (B_L0 + 33554432)         // f32  [n][c][t]
#define B_END  (B_G1P + 262144)

typedef short bf16x8 __attribute__((ext_vector_type(8)));
typedef float f32x4  __attribute__((ext_vector_type(4)));

__device__ __forceinline__ float bf2f(u16 u) { return __uint_as_float(((u32)u) << 16); }
__device__ __forceinline__ u16 f2bf(float f) {
    u32 x = __float_as_uint(f);
    return (u16)((x + 0x7fffu + ((x >> 16) & 1u)) >> 16);
}
__device__ __forceinline__ float ldin(const void* p, u32 i, int f32) {
    return f32 ? ((const float*)p)[i] : bf2f(((const u16*)p)[i]);
}

// ---------------- dtype detect (bf16 vs f32 input buffers) ----------------
__global__ void k_detect(const void* a, int* flag) {
    if (threadIdx.x == 0 && blockIdx.x == 0) {
        const u16* p = (const u16*)a;
        int cnt = 0;
        for (int i = 0; i < 64; ++i) {
            float v = bf2f(p[2 * i]);
            if (v >= 0.f && v <= 1.0f) ++cnt;
        }
        *flag = (cnt >= 56) ? 0 : 1;
    }
}

// ---------------- param prep: BN folds + bf16 MFMA weight layouts ----------------
__global__ void k_prep(const void* dbn_g, const void* dbn_b, const void* dbn_m, const void* dbn_v,
                       const void* w0, const void* bw0,
                       const void* g0a, const void* b0a, const void* m0a, const void* v0a,
                       const void* bt0, const void* g0b, const void* b0b, const void* m0b, const void* v0b,
                       const void* w1, const void* bw1,
                       const void* g1a, const void* b1a, const void* m1a, const void* v1a,
                       const void* bt1, const void* g1b, const void* b1b, const void* m1b, const void* v1b,
                       const void* wt0,
                       float* P, u16* W0A, u16* WTA, const int* flagp)
{
    const int f32 = *flagp;
    int i = blockIdx.x * 256 + threadIdx.x;
    if (i < 33792) {
        float s = ldin(dbn_g, i, f32) * rsqrtf(ldin(dbn_v, i, f32) + EPS_);
        P[OFF_DBN_S + i] = s;
        P[OFF_DBN_O + i] = ldin(dbn_b, i, f32) - ldin(dbn_m, i, f32) * s;
    } else if (i < 50688) { int j = i - 33792; P[OFF_W0 + j] = ldin(w0, j, f32); }
    else if (i < 50752) { int j = i - 50688; P[OFF_BW0 + j] = ldin(bw0, j, f32); }
    else if (i < 50816) { int j = i - 50752;
        float s = ldin(g0a, j, f32) * rsqrtf(ldin(v0a, j, f32) + EPS_);
        P[OFF_A0S + j] = s; P[OFF_A0O + j] = ldin(b0a, j, f32) - ldin(m0a, j, f32) * s;
    } else if (i < 50880) { int j = i - 50816;
        float s = ldin(g0b, j, f32) * rsqrtf(ldin(v0b, j, f32) + EPS_);
        P[OFF_B0S + j] = s; P[OFF_B0O + j] = (ldin(bt0, j, f32) - ldin(m0b, j, f32)) * s + ldin(b0b, j, f32);
    } else if (i < 54976) { int j = i - 50880; P[OFF_W1 + j] = ldin(w1, j, f32); }
    else if (i < 55040) { int j = i - 54976; P[OFF_BW1 + j] = ldin(bw1, j, f32); }
    else if (i < 55104) { int j = i - 55040;
        float s = ldin(g1a, j, f32) * rsqrtf(ldin(v1a, j, f32) + EPS_);
        P[OFF_A1S + j] = s; P[OFF_A1O + j] = ldin(b1a, j, f32) - ldin(m1a, j, f32) * s;
    } else if (i < 55168) { int j = i - 55104;
        float s = ldin(g1b, j, f32) * rsqrtf(ldin(v1b, j, f32) + EPS_);
        P[OFF_B1S + j] = s; P[OFF_B1O + j] = (ldin(bt1, j, f32) - ldin(m1b, j, f32)) * s + ldin(b1b, j, f32);
    } else if (i < 73600) {      // W0A[c][288]: w0^T, row 264 = bw0 (bias trick), 265.. = 0
        int j = i - 55168; int c = j / 288, ci = j - c * 288;
        float val = (ci < 264) ? ldin(w0, (u32)ci * 64 + c, f32)
                  : ((ci == 264) ? ldin(bw0, c, f32) : 0.f);
        W0A[j] = f2bf(val);
    } else if (i < 110464) {     // WTA[k][o][i] = wt0[k][0][i][o]
        int j = i - 73600; int k = j >> 12, rem = j & 4095, o = rem >> 6, ii = rem & 63;
        WTA[j] = f2bf(ldin(wt0, ((u32)(k * 64 + ii)) * 64 + o, f32));
    }
}

// ---------------- MFMA pw0: concat+BN+reshape gather -> X^T tile; D[v][c] = X^T . W0A^T ----------------
// grid (t2, n, vhalf). M=64 (v), N=64 (c), K=288. b-frags straight from global W0A (L2-hot).
__global__ __launch_bounds__(256) void k_pw0(const void* __restrict__ xin, const void* __restrict__ bin,
                                             const void* __restrict__ cin2, const float* __restrict__ P,
                                             const u16* __restrict__ W0Ag, u16* __restrict__ h0,
                                             const int* __restrict__ flagp)
{
    __shared__ __align__(16) u16 XT[64 * 296];
    const int f32 = *flagp;
    const int t2 = blockIdx.x, n = blockIdx.y, vh = blockIdx.z;
    const int tid = threadIdx.x;
    const int vbase = vh * 64;
    for (int e = tid; e < 288 * 64; e += 256) {
        int c2 = e >> 6, vloc = e & 63;
        int vv = vbase + vloc;
        float val;
        if (c2 < 264) {
            u32 L = (u32)c2 * 4096u + (u32)t2 * 128u + (u32)vv;
            u32 vs = L / 8448u;
            u32 r  = L - vs * 8448u;
            u32 ts = r / 264u;
            u32 cc = r - ts * 264u;
            u32 base = ((u32)n * 32u + ts) * 128u + vs;
            if (cc < 256u)      val = ldin(xin, base * 256u + cc, f32);
            else if (cc < 260u) val = ldin(bin, base * 4u + (cc - 256u), f32);
            else                val = ldin(cin2, base * 4u + (cc - 260u), f32);
            u32 ch = vs * 264u + cc;
            val = fmaf(val, P[OFF_DBN_S + ch], P[OFF_DBN_O + ch]);
        } else val = (c2 == 264) ? 1.0f : 0.0f;
        XT[vloc * 296 + c2] = f2bf(val);
    }
    __syncthreads();
    const int wv = tid >> 6, lane = tid & 63, l16 = lane & 15, quad = lane >> 4;
    const int m0 = wv * 16;
    f32x4 acc[4];
#pragma unroll
    for (int i = 0; i < 4; ++i) acc[i] = (f32x4){0.f, 0.f, 0.f, 0.f};
    for (int ks = 0; ks < 9; ++ks) {
        const int k0 = ks * 32 + quad * 8;
        bf16x8 af = *(const bf16x8*)&XT[(m0 + l16) * 296 + k0];
#pragma unroll
        for (int ni = 0; ni < 4; ++ni) {
            bf16x8 bf = *(const bf16x8*)&W0Ag[(u32)(ni * 16 + l16) * 288 + k0];
            acc[ni] = __builtin_amdgcn_mfma_f32_16x16x32_bf16(af, bf, acc[ni], 0, 0, 0);
        }
    }
    const int v = vbase + m0 + quad * 4;
#pragma unroll
    for (int ni = 0; ni < 4; ++ni) {
        int c = ni * 16 + l16;
        ushort4 rr; u16* rp = (u16*)&rr;
#pragma unroll
        for (int r = 0; r < 4; ++r) rp[r] = f2bf(acc[ni][r]);
        *(ushort4*)&h0[((u32)(n * 64 + c) * 32 + t2) * 128 + v] = rr;
    }
}

// ---------------- MFMA graph0 + BN0a + PReLU -> g0[n][t][v][i] ----------------
// per (n,t): G[c][w] = H[c][v] . AM[v][w]. M=c=64, N=w=128, K=v=128.
__global__ __launch_bounds__(256) void k_graph0(const void* __restrict__ a, const void* __restrict__ imp0,
                                                const void* __restrict__ al0, const float* __restrict__ P,
                                                const u16* __restrict__ h0, u16* __restrict__ g0,
                                                const int* __restrict__ flagp)
{
    __shared__ __align__(16) u16 amT[128 * 136];
    __shared__ __align__(16) u16 Hs[64 * 136];
    const int f32 = *flagp;
    const int t = blockIdx.x, n = blockIdx.y;
    const int tid = threadIdx.x;
    const u32 abase = (((u32)n * T_ + t) * V_) * V_;
    for (int e = tid; e < 128 * 128; e += 256) {
        int vv = e >> 7, w = e & 127;
        float av = ldin(a, abase + (u32)vv * 128u + w, f32) * ldin(imp0, (u32)vv * 128u + w, f32);
        amT[w * 136 + vv] = f2bf(av);
    }
    for (int e = tid; e < 1024; e += 256) {       // 64x128 bf16 in 16B chunks
        int c = e >> 4, ch = e & 15;
        *(uint4*)&Hs[c * 136 + ch * 8] = *(const uint4*)&h0[((u32)(n * 64 + c) * 32 + t) * 128 + ch * 8];
    }
    __syncthreads();
    const int wv = tid >> 6, lane = tid & 63, l16 = lane & 15, quad = lane >> 4;
    const int n0w = wv * 32;
    f32x4 acc[4][2];
#pragma unroll
    for (int mi = 0; mi < 4; ++mi) { acc[mi][0] = (f32x4){0,0,0,0}; acc[mi][1] = (f32x4){0,0,0,0}; }
#pragma unroll
    for (int ks = 0; ks < 4; ++ks) {
        const int k0 = ks * 32 + quad * 8;
        bf16x8 bf[2];
        bf[0] = *(const bf16x8*)&amT[(n0w + l16) * 136 + k0];
        bf[1] = *(const bf16x8*)&amT[(n0w + 16 + l16) * 136 + k0];
#pragma unroll
        for (int mi = 0; mi < 4; ++mi) {
            bf16x8 af = *(const bf16x8*)&Hs[(mi * 16 + l16) * 136 + k0];
            acc[mi][0] = __builtin_amdgcn_mfma_f32_16x16x32_bf16(af, bf[0], acc[mi][0], 0, 0, 0);
            acc[mi][1] = __builtin_amdgcn_mfma_f32_16x16x32_bf16(af, bf[1], acc[mi][1], 0, 0, 0);
        }
    }
#pragma unroll
    for (int mi = 0; mi < 4; ++mi) {
        const int c0 = mi * 16 + quad * 4;
        const float4 s4 = *(const float4*)&P[OFF_A0S + c0];
        const float4 o4 = *(const float4*)&P[OFF_A0O + c0];
        const float ss[4] = {s4.x, s4.y, s4.z, s4.w};
        const float oo[4] = {o4.x, o4.y, o4.z, o4.w};
#pragma unroll
        for (int ni = 0; ni < 2; ++ni) {
            const int w = n0w + ni * 16 + l16;
            ushort4 rr; u16* rp = (u16*)&rr;
#pragma unroll
            for (int r = 0; r < 4; ++r) {
                float y = fmaf(acc[mi][ni][r], ss[r], oo[r]);
                float alv = ldin(al0, ((u32)(c0 + r) * 32 + t) * 128 + w, f32);
                rp[r] = f2bf((y >= 0.f) ? y : alv * y);
            }
            *(ushort4*)&g0[((u32)(n * 32 + t) * 128 + w) * 64 + c0] = rr;
        }
    }
}

// ---------------- MFMA tconv0 (K=9 taps) + BN0b(+bt0) -> L0 f32 ----------------
// per (n,t): O[o][v] = sum_k WTA[k] . g0slice[t+k-4]. Double-buffered 16KB B-slices.
__global__ __launch_bounds__(256) void k_tconv0(const u16* __restrict__ WTAg, const float* __restrict__ P,
                                                const u16* __restrict__ g0, float* __restrict__ L0)
{
    __shared__ __align__(16) u16 Wl[2][64 * 72];
    __shared__ __align__(16) u16 Bs[2][128 * 72];
    const int t = blockIdx.x, n = blockIdx.y;
    const int tid = threadIdx.x;
    const int kmin = (t < 4) ? (4 - t) : 0;
    const int kmax = (t > 27) ? (35 - t) : 8;

    auto stageB = [&](int k, int buf) {
        const u16* src = g0 + ((u32)(n * 32 + (t + k - 4)) * 128) * 64;
        for (int e = tid; e < 1024; e += 256) {
            int row = e >> 3, ch = e & 7;
            *(uint4*)&Bs[buf][row * 72 + ch * 8] = *(const uint4*)&src[row * 64 + ch * 8];
        }
    };
    auto stageW = [&](int k, int buf) {
        const u16* src = WTAg + (u32)k * 4096;
        for (int e = tid; e < 512; e += 256) {
            int row = e >> 3, ch = e & 7;
            *(uint4*)&Wl[buf][row * 72 + ch * 8] = *(const uint4*)&src[row * 64 + ch * 8];
        }
    };
    stageB(kmin, 0); stageW(kmin, 0);
    __syncthreads();
    const int wv = tid >> 6, lane = tid & 63, l16 = lane & 15, quad = lane >> 4;
    const int n0w = wv * 32;
    f32x4 acc[4][2];
#pragma unroll
    for (int mi = 0; mi < 4; ++mi) { acc[mi][0] = (f32x4){0,0,0,0}; acc[mi][1] = (f32x4){0,0,0,0}; }

    for (int k = kmin; k <= kmax; ++k) {
        const int buf = (k - kmin) & 1;
        if (k < kmax) { stageB(k + 1, buf ^ 1); stageW(k + 1, buf ^ 1); }
#pragma unroll
        for (int ks = 0; ks < 2; ++ks) {
            const int k0 = ks * 32 + quad * 8;
            bf16x8 bf[2];
            bf[0] = *(const bf16x8*)&Bs[buf][(n0w + l16) * 72 + k0];
            bf[1] = *(const bf16x8*)&Bs[buf][(n0w + 16 + l16) * 72 + k0];
#pragma unroll
            for (int mi = 0; mi < 4; ++mi) {
                bf16x8 af = *(const bf16x8*)&Wl[buf][(mi * 16 + l16) * 72 + k0];
                acc[mi][0] = __builtin_amdgcn_mfma_f32_16x16x32_bf16(af, bf[0], acc[mi][0], 0, 0, 0);
                acc[mi][1] = __builtin_amdgcn_mfma_f32_16x16x32_bf16(af, bf[1], acc[mi][1], 0, 0, 0);
            }
        }
        __syncthreads();
    }
#pragma unroll
    for (int mi = 0; mi < 4; ++mi) {
        const int ob = mi * 16 + quad * 4;
        const float4 s4 = *(const float4*)&P[OFF_B0S + ob];
        const float4 o4 = *(const float4*)&P[OFF_B0O + ob];
        const float ss[4] = {s4.x, s4.y, s4.z, s4.w};
        const float oo[4] = {o4.x, o4.y, o4.z, o4.w};
#pragma unroll
        for (int ni = 0; ni < 2; ++ni) {
            const int v = n0w + ni * 16 + l16;
#pragma unroll
            for (int r = 0; r < 4; ++r)
                L0[((u32)(n * 64 + ob + r) * 32 + t) * 128 + v] = fmaf(acc[mi][ni][r], ss[r], oo[r]);
        }
    }
}

// ---------------- pointwise conv 1 + graph conv 1 (w=0 only) + BN1a + PReLU -> g1p ----------------
__global__ __launch_bounds__(128) void k_pw1(const void* __restrict__ a, const void* __restrict__ imp1,
                                             const void* __restrict__ al1, const float* __restrict__ P,
                                             const float* __restrict__ L0, float* __restrict__ g1p,
                                             const int* __restrict__ flagp)
{
    __shared__ float part[V_ * 65];
    __shared__ float red2[128];
    const int f32 = *flagp;
    const int t = blockIdx.x, n = blockIdx.y;
    const int tid = threadIdx.x;
    const int v = tid;
    float acc[CO_];
#pragma unroll
    for (int o = 0; o < CO_; ++o) acc[o] = P[OFF_BW1 + o];
    const float* W = P + OFF_W1;
    const u32 base = (u32)n * (CO_ * T_ * V_) + (u32)t * V_ + (u32)v;
    for (int c = 0; c < CO_; ++c) {
        float xv = L0[base + (u32)c * (T_ * V_)];
        const float* wr = W + c * CO_;
#pragma unroll
        for (int o = 0; o < CO_; ++o) acc[o] = fmaf(xv, wr[o], acc[o]);
    }
    float amv = ldin(a, (((u32)n * T_ + t) * V_ + v) * V_ + 0u, f32) * ldin(imp1, (u32)v * V_ + 0u, f32);
#pragma unroll
    for (int o = 0; o < CO_; ++o) part[v * 65 + o] = acc[o] * amv;
    __syncthreads();
    const int o = tid & 63, hh = tid >> 6;
    float s = 0.f;
    for (int vv = hh * 64; vv < hh * 64 + 64; ++vv) s += part[vv * 65 + o];
    red2[tid] = s;
    __syncthreads();
    if (tid < 64) {
        float g = red2[tid] + red2[64 + tid];
        float y = fmaf(g, P[OFF_A1S + o], P[OFF_A1O + o]);
        float alv = ldin(al1, ((u32)o * T_ + t) * V_ + 0u, f32);
        y = (y >= 0.f) ? y : alv * y;
        g1p[((u32)n * CO_ + o) * T_ + t] = y;
    }
}

// ---------------- temporal conv 1 (v=0 only) + BN1b(+bt1) + residual + transpose-out ----------------
__global__ __launch_bounds__(64) void k_tconv1(const void* __restrict__ wt1, const float* __restrict__ P,
                                               const float* __restrict__ g1p, const float* __restrict__ L0,
                                               void* __restrict__ out, const int* __restrict__ flagp)
{
    __shared__ float gl[CO_ * KT_];
    const int f32 = *flagp;
    const int t = blockIdx.x, n = blockIdx.y;
    const int tid = threadIdx.x;
    for (int e = tid; e < CO_ * KT_; e += 64) {
        int i = e / KT_, kk = e - i * KT_;
        int tt = t + kk - 4;
        gl[e] = (tt >= 0 && tt < T_) ? g1p[((u32)n * CO_ + i) * T_ + tt] : 0.f;
    }
    __syncthreads();
    float acc = 0.f;
    for (int i = 0; i < CO_; ++i) {
#pragma unroll
        for (int k = 0; k < KT_; ++k) {
            float wv = ldin(wt1, ((u32)(k * CO_ + i)) * CO_ + tid, f32);
            acc = fmaf(gl[i * KT_ + k], wv, acc);
        }
    }
    float y = fmaf(acc, P[OFF_B1S + tid], P[OFF_B1O + tid]);
    y += L0[(u32)n * (CO_ * T_ * V_) + (u32)tid * (T_ * V_) + (u32)t * V_ + 0];
    const u32 oi = ((u32)n * T_ + t) * CO_ + tid;
    if (f32) ((float*)out)[oi] = y;
    else     ((u16*)out)[oi]   = f2bf(y);
}

__global__ void k_fail(u16* out, int nel) {
    int i = blockIdx.x * 256 + threadIdx.x;
    if (i < nel) out[i] = 0x7f80; // +inf marker: ws too small
}

extern "C" void kernel_launch(void* const* d_in, const int* in_sizes, int n_in,
                              void* d_out, int out_size, void* d_ws, size_t ws_size,
                              hipStream_t stream)
{
    const void* xin  = d_in[0];
    const void* bin  = d_in[1];
    const void* cin2 = d_in[2];
    const void* a    = d_in[3];
    const void* dbn_g = d_in[4];
    const void* dbn_b = d_in[5];
    const void* dbn_m = d_in[6];
    const void* dbn_v = d_in[7];
    const void* w0  = d_in[8];
    const void* bw0 = d_in[9];
    const void* imp0 = d_in[10];
    const void* g0a = d_in[11];
    const void* b0a = d_in[12];
    const void* m0a = d_in[13];
    const void* v0a = d_in[14];
    const void* al0 = d_in[15];
    const void* wt0 = d_in[16];
    const void* bt0 = d_in[17];
    const void* g0b = d_in[18];
    const void* b0b = d_in[19];
    const void* m0b = d_in[20];
    const void* v0b = d_in[21];
    const void* w1  = d_in[22];
    const void* bw1 = d_in[23];
    const void* imp1 = d_in[24];
    const void* g1a = d_in[25];
    const void* b1a = d_in[26];
    const void* m1a = d_in[27];
    const void* v1a = d_in[28];
    const void* al1 = d_in[29];
    const void* wt1 = d_in[30];
    const void* bt1 = d_in[31];
    const void* g1b = d_in[32];
    const void* b1b = d_in[33];
    const void* m1b = d_in[34];
    const void* v1b = d_in[35];

    if (ws_size < (size_t)B_END) {
        k_fail<<<(out_size + 255) / 256, 256, 0, stream>>>((u16*)d_out, out_size);
        return;
    }
    char* w = (char*)d_ws;
    float* P    = (float*)(w + B_P);
    int*   flg  = (int*)(w + B_FLAG);
    u16*   W0A  = (u16*)(w + B_W0A);
    u16*   WTA  = (u16*)(w + B_WTA);
    u16*   h0   = (u16*)(w + B_H0);
    u16*   g0   = (u16*)(w + B_G0);
    float* L0   = (float*)(w + B_L0);
    float* g1p  = (float*)(w + B_G1P);

    k_detect<<<1, 64, 0, stream>>>(a, flg);
    k_prep<<<(PREP_TOTAL + 255) / 256, 256, 0, stream>>>(
        dbn_g, dbn_b, dbn_m, dbn_v, w0, bw0, g0a, b0a, m0a, v0a,
        bt0, g0b, b0b, m0b, v0b, w1, bw1, g1a, b1a, m1a, v1a,
        bt1, g1b, b1b, m1b, v1b, wt0, P, W0A, WTA, flg);

    dim3 gpw0(T_, N_, 2);
    dim3 grid(T_, N_);
    k_pw0   <<<gpw0, 256, 0, stream>>>(xin, bin, cin2, P, W0A, h0, flg);
    k_graph0<<<grid, 256, 0, stream>>>(a, imp0, al0, P, h0, g0, flg);
    k_tconv0<<<grid, 256, 0, stream>>>(WTA, P, g0, L0);
    k_pw1   <<<grid, 128, 0, stream>>>(a, imp1, al1, P, L0, g1p, flg);
    k_tconv1<<<grid,  64, 0, stream>>>(wt1, P, g1p, L0, d_out, flg);
}